// Round 3
// baseline (919.048 us; speedup 1.0000x reference)
//
#include <hip/hip_runtime.h>

#define BB 8
#define TT 4096
#define DD 768
#define MM (BB*TT)   // 32768

typedef _Float16 f16;
typedef _Float16 f16x8 __attribute__((ext_vector_type(8)));
typedef float f32x4 __attribute__((ext_vector_type(4)));
typedef float f32x16 __attribute__((ext_vector_type(16)));

typedef __attribute__((address_space(1))) void void_g;
typedef __attribute__((address_space(3))) void void_l;

// async global->LDS, 16B per lane. LDS dest = wave-uniform base + lane*16.
__device__ __forceinline__ void gload16(const void* g, void* l) {
  __builtin_amdgcn_global_load_lds((void_g*)g, (void_l*)l, 16, 0, 0);
}

// ---------------- projection GEMM: C[m,n] = sum_k A[m,k]*W[n,k] + bias[n] --
// A: MMxDD f32, W: DDxDD f32 (both converted to f16 during reg-staging)
__global__ __launch_bounds__(256)
void proj_gemm(const float* __restrict__ Af, const float* __restrict__ Wf,
               const float* __restrict__ bias, f16* __restrict__ C) {
  __shared__ f16 As[128 * 32];
  __shared__ f16 Ws[128 * 32];
  const int m0 = blockIdx.x * 128;
  const int n0 = blockIdx.y * 128;
  const int t = threadIdx.x;
  const int lane = t & 63;
  const int w = t >> 6;
  const int wm = (w >> 1) * 64;
  const int wn = (w & 1) * 64;
  const int fr = lane & 15, fq = lane >> 4;
  const int xst = ((t >> 3) & 3) << 3;   // store-side swizzle (row = t>>2)
  const int xrd = ((fr >> 1) & 3) << 3;  // read-side swizzle (row = ..+fr)

  f32x4 acc[4][4] = {};

  // staging element indices (tile 128 rows x 32 cols): e0 rows 0..63, e1 rows 64..127
  const int e0 = t * 8;
  const int r0 = t >> 2, cW = (t & 3) * 8;
  const int e1 = 2048 + t * 8;

  for (int ks = 0; ks < 24; ++ks) {
    const int k0 = ks * 32;
    // reg-stage W tile with f32->f16 conversion (swizzled store)
    {
      const float* g0 = Wf + (size_t)(n0 + r0) * DD + k0 + cW;
      const float* g1 = Wf + (size_t)(n0 + 64 + r0) * DD + k0 + cW;
      float4 x0 = *(const float4*)g0, x1 = *(const float4*)(g0 + 4);
      float4 y0 = *(const float4*)g1, y1 = *(const float4*)(g1 + 4);
      f16x8 va, vb;
      va[0] = (f16)x0.x; va[1] = (f16)x0.y; va[2] = (f16)x0.z; va[3] = (f16)x0.w;
      va[4] = (f16)x1.x; va[5] = (f16)x1.y; va[6] = (f16)x1.z; va[7] = (f16)x1.w;
      vb[0] = (f16)y0.x; vb[1] = (f16)y0.y; vb[2] = (f16)y0.z; vb[3] = (f16)y0.w;
      vb[4] = (f16)y1.x; vb[5] = (f16)y1.y; vb[6] = (f16)y1.z; vb[7] = (f16)y1.w;
      *(f16x8*)&Ws[e0 ^ xst] = va;
      *(f16x8*)&Ws[e1 ^ xst] = vb;
    }
    // reg-stage A tile with f32->f16 conversion (swizzled store)
    {
      const float* g0 = Af + (size_t)(m0 + r0) * DD + k0 + cW;
      const float* g1 = Af + (size_t)(m0 + 64 + r0) * DD + k0 + cW;
      float4 x0 = *(const float4*)g0, x1 = *(const float4*)(g0 + 4);
      float4 y0 = *(const float4*)g1, y1 = *(const float4*)(g1 + 4);
      f16x8 va, vb;
      va[0] = (f16)x0.x; va[1] = (f16)x0.y; va[2] = (f16)x0.z; va[3] = (f16)x0.w;
      va[4] = (f16)x1.x; va[5] = (f16)x1.y; va[6] = (f16)x1.z; va[7] = (f16)x1.w;
      vb[0] = (f16)y0.x; vb[1] = (f16)y0.y; vb[2] = (f16)y0.z; vb[3] = (f16)y0.w;
      vb[4] = (f16)y1.x; vb[5] = (f16)y1.y; vb[6] = (f16)y1.z; vb[7] = (f16)y1.w;
      *(f16x8*)&As[e0 ^ xst] = va;
      *(f16x8*)&As[e1 ^ xst] = vb;
    }
    __syncthreads();

    f16x8 a[4], b[4];
#pragma unroll
    for (int i = 0; i < 4; ++i)
      a[i] = *(const f16x8*)&As[(((wm + i * 16 + fr) * 32) + fq * 8) ^ xrd];
#pragma unroll
    for (int j = 0; j < 4; ++j)
      b[j] = *(const f16x8*)&Ws[(((wn + j * 16 + fr) * 32) + fq * 8) ^ xrd];
#pragma unroll
    for (int i = 0; i < 4; ++i)
#pragma unroll
      for (int j = 0; j < 4; ++j)
        acc[i][j] = __builtin_amdgcn_mfma_f32_16x16x32_f16(a[i], b[j], acc[i][j], 0, 0, 0);
    __syncthreads();
  }

  // epilogue: C/D layout col=lane&15, row=(lane>>4)*4+reg
#pragma unroll
  for (int j = 0; j < 4; ++j) {
    const int col = n0 + wn + j * 16 + fr;
    const float bv = bias[col];
#pragma unroll
    for (int i = 0; i < 4; ++i) {
#pragma unroll
      for (int r = 0; r < 4; ++r) {
        const int row = m0 + wm + i * 16 + fq * 4 + r;
        C[(size_t)row * DD + col] = (f16)(acc[i][j][r] + bv);
      }
    }
  }
}

// ---------------- mask -> additive bias ----------------
__global__ void mk_bias(const int* __restrict__ mask, float* __restrict__ mb, int n) {
  int i = blockIdx.x * 256 + threadIdx.x;
  if (i < n) mb[i] = mask[i] ? 0.f : -1e30f;
}

// ---------------- flash stats v2: 32x32x16 MFMA, R2xC4 per wave ------------
// Block: 512 thr = 8 waves, wave grid 4q x 2k. Block tile 256q x 256k.
// Grid 256: bb=bid&7 (batch->XCD), qs=(bid>>3)&15, kh=bid>>7 (k half).
// Each block sweeps kt=0..7 (k-tiles of 256 within its 2048 half),
// d in 24 chunks of 32. K tile [256][32] f16 in LDS (XOR swizzled),
// Q A-frags read direct from global (L2-resident).
__global__ __launch_bounds__(512, 2)
void attn2(const f16* __restrict__ Q, const f16* __restrict__ K,
           const float* __restrict__ mbias, float* __restrict__ pmv,
           float* __restrict__ pzv, float* __restrict__ sdg) {
  __shared__ f16 Ks[2][256 * 32];
  __shared__ float msm[8][64];
  __shared__ float zsm[8][64];
  const int bid = blockIdx.x;
  const int bb = bid & 7, qs = (bid >> 3) & 15, kh = bid >> 7;
  const int t = threadIdx.x, lane = t & 63, w = t >> 6;
  const int wq = w >> 1, wk = w & 1;
  const int l31 = lane & 31, hi = lane >> 5;
  const int q0 = qs * 256;
  const float scale = 0.036084391824351613f;  // 1/sqrt(768)

  const f16* Qg = Q + (size_t)bb * TT * DD + (size_t)q0 * DD;
  const f16* Kg = K + (size_t)bb * TT * DD + (size_t)kh * 2048 * DD;

  // staging constants: per thread covers rows r0 / r0+128, swizzled source col c0
  const int r0 = t >> 2;
  const int c0 = (((t & 3) ^ ((t >> 3) & 3)) << 3);
  // read-side element swizzle
  const int xsw = ((l31 >> 1) & 3) << 3;

  msm[w][lane] = -1e4f;
  zsm[w][lane] = 0.f;

  // A-row base pointers (Q direct from global)
  const f16* Arow0 = Qg + (size_t)(wq * 64 + l31) * DD + hi * 8;
  const f16* Arow1 = Arow0 + (size_t)32 * DD;

  f32x16 acc[2][4] = {};
  float mbv[4] = {};

#define STAGE_K(buf, ktb, d0_) do { \
    const f16* ks_ = Kg + (size_t)((ktb) + r0) * DD + (d0_) + c0; \
    gload16(ks_, &Ks[buf][w * 512]); \
    gload16(ks_ + (size_t)128 * DD, &Ks[buf][4096 + w * 512]); \
  } while (0)

  STAGE_K(0, 0, 0);
  __syncthreads();

  int kt = 0, dc = 0;
  for (int p = 0; p < 192; ++p) {
    const int cur = p & 1;
    int ndc = dc + 1, nkt = kt;
    if (ndc == 24) { ndc = 0; ++nkt; }
    if (nkt < 8) STAGE_K(cur ^ 1, nkt * 256, ndc * 32);

    const int d0 = dc * 32;
#pragma unroll
    for (int ks = 0; ks < 2; ++ks) {
      f16x8 a0 = *(const f16x8*)(Arow0 + d0 + ks * 16);
      f16x8 a1 = *(const f16x8*)(Arow1 + d0 + ks * 16);
      f16x8 bf[4];
#pragma unroll
      for (int cb = 0; cb < 4; ++cb)
        bf[cb] = *(const f16x8*)&Ks[cur][(((wk * 128 + cb * 32 + l31) * 32) + ks * 16 + hi * 8) ^ xsw];
#pragma unroll
      for (int cb = 0; cb < 4; ++cb) {
        acc[0][cb] = __builtin_amdgcn_mfma_f32_32x32x16_f16(a0, bf[cb], acc[0][cb], 0, 0, 0);
        acc[1][cb] = __builtin_amdgcn_mfma_f32_32x32x16_f16(a1, bf[cb], acc[1][cb], 0, 0, 0);
      }
    }

    if (dc == 22) {
#pragma unroll
      for (int cb = 0; cb < 4; ++cb)
        mbv[cb] = mbias[bb * TT + kh * 2048 + kt * 256 + wk * 128 + cb * 32 + l31];
    }

    if (dc == 23) {
      const int colbase = kh * 2048 + kt * 256 + wk * 128 + l31;
#pragma unroll
      for (int rb = 0; rb < 2; ++rb) {
#pragma unroll
        for (int reg = 0; reg < 16; ++reg) {
          const int rloc = (reg & 3) + 8 * (reg >> 2) + 4 * hi;
          const int rs = rb * 32 + rloc;
          float v0 = fmaf(acc[rb][0][reg], scale, mbv[0]);
          float v1 = fmaf(acc[rb][1][reg], scale, mbv[1]);
          float v2 = fmaf(acc[rb][2][reg], scale, mbv[2]);
          float v3 = fmaf(acc[rb][3][reg], scale, mbv[3]);
          float tmax = fmaxf(fmaxf(v0, v1), fmaxf(v2, v3));
#pragma unroll
          for (int off = 1; off < 32; off <<= 1)
            tmax = fmaxf(tmax, __shfl_xor(tmax, off));
          const float mo = msm[w][rs];
          const float mn = fmaxf(mo, tmax);
          float pr = __expf(v0 - mn) + __expf(v1 - mn) + __expf(v2 - mn) + __expf(v3 - mn);
#pragma unroll
          for (int off = 1; off < 32; off <<= 1)
            pr += __shfl_xor(pr, off);
          if (l31 == 0) {
            msm[w][rs] = mn;
            zsm[w][rs] = zsm[w][rs] * __expf(mo - mn) + pr;
          }
          // diagonal capture (position-unique across the whole grid)
          const int qrow = q0 + wq * 64 + rs;
          if (colbase == qrow)          sdg[bb * TT + qrow] = v0;
          if (colbase + 32 == qrow)     sdg[bb * TT + qrow] = v1;
          if (colbase + 64 == qrow)     sdg[bb * TT + qrow] = v2;
          if (colbase + 96 == qrow)     sdg[bb * TT + qrow] = v3;
        }
      }
#pragma unroll
      for (int rb = 0; rb < 2; ++rb)
#pragma unroll
        for (int cb = 0; cb < 4; ++cb)
          acc[rb][cb] = (f32x16)(0.f);
    }

    __syncthreads();
    kt = nkt; dc = ndc;
  }
#undef STAGE_K

  // write this wave's (m,Z) partials: 64 rows per wave
  {
    const int qrow = q0 + wq * 64 + lane;
    const int pidx = (kh * 2 + wk) * MM + bb * TT + qrow;
    pmv[pidx] = msm[w][lane];
    pzv[pidx] = zsm[w][lane];
  }
}

// ---------------- merge 4 partials -> wdiag ----------------
__global__ void merge_stats(const float* __restrict__ pm, const float* __restrict__ pz,
                            const float* __restrict__ sdg, float* __restrict__ wdiag) {
  int i = blockIdx.x * 256 + threadIdx.x;
  if (i >= MM) return;
  float m0 = pm[i], m1 = pm[MM + i], m2 = pm[2 * MM + i], m3 = pm[3 * MM + i];
  float m = fmaxf(fmaxf(m0, m1), fmaxf(m2, m3));
  float Z = pz[i] * __expf(m0 - m) + pz[MM + i] * __expf(m1 - m) +
            pz[2 * MM + i] * __expf(m2 - m) + pz[3 * MM + i] * __expf(m3 - m);
  wdiag[i] = __expf(sdg[i] - m) / Z;
}

// ---------------- output ----------------
__global__ void zero_out(float* out, int n) {
  int i = blockIdx.x * 256 + threadIdx.x;
  if (i < n) out[i] = 0.f;
}

// out[b,d] = sum_t X[b,t,d] * wdiag[b,t]
__global__ __launch_bounds__(256)
void out_gemv(const float* __restrict__ X, const float* __restrict__ wdiag,
              float* __restrict__ out) {
  __shared__ float wsm[256];
  const int b = blockIdx.z;
  const int d = blockIdx.y * 256 + threadIdx.x;
  const int tbase = blockIdx.x * 256;
  wsm[threadIdx.x] = wdiag[b * TT + tbase + threadIdx.x];
  __syncthreads();
  float acc = 0.f;
  const float* xp = X + (size_t)(b * TT + tbase) * DD + d;
#pragma unroll 4
  for (int i = 0; i < 256; ++i) acc += xp[(size_t)i * DD] * wsm[i];
  atomicAdd(&out[b * DD + d], acc);
}

extern "C" void kernel_launch(void* const* d_in, const int* in_sizes, int n_in,
                              void* d_out, int out_size, void* d_ws, size_t ws_size,
                              hipStream_t stream) {
  const float* X    = (const float*)d_in[0];
  const int*   mask = (const int*)d_in[1];
  const float* Wq_w = (const float*)d_in[2];
  const float* Wq_b = (const float*)d_in[3];
  const float* Wk_w = (const float*)d_in[4];
  const float* Wk_b = (const float*)d_in[5];
  float* out = (float*)d_out;

  // workspace layout (~97.4 MB)
  f16* Qh  = (f16*)d_ws;
  f16* Kh  = Qh + (size_t)MM * DD;
  float* mbias = (float*)(Kh + (size_t)MM * DD);
  float* pm    = mbias + MM;
  float* pz    = pm + 4 * (size_t)MM;
  float* sdg   = pz + 4 * (size_t)MM;
  float* wdiag = sdg + MM;

  proj_gemm<<<dim3(256, 6), 256, 0, stream>>>(X, Wq_w, Wq_b, Qh);
  proj_gemm<<<dim3(256, 6), 256, 0, stream>>>(X, Wk_w, Wk_b, Kh);

  mk_bias<<<128, 256, 0, stream>>>(mask, mbias, MM);

  attn2<<<256, 512, 0, stream>>>(Qh, Kh, mbias, pm, pz, sdg);

  merge_stats<<<128, 256, 0, stream>>>(pm, pz, sdg, wdiag);

  zero_out<<<24, 256, 0, stream>>>(out, BB * DD);
  out_gemv<<<dim3(16, 3, 8), 256, 0, stream>>>(X, wdiag, out);
}

// Round 4
// 470.438 us; speedup vs baseline: 1.9536x; 1.9536x over previous
//
#include <hip/hip_runtime.h>

#define BB 8
#define TT 4096
#define DD 768
#define MM (BB*TT)   // 32768

typedef _Float16 f16;
typedef _Float16 f16x8 __attribute__((ext_vector_type(8)));
typedef float f32x4 __attribute__((ext_vector_type(4)));

typedef __attribute__((address_space(1))) void void_g;
typedef __attribute__((address_space(3))) void void_l;

// async global->LDS, 16B per lane. LDS dest = wave-uniform base + lane*16 (linear).
__device__ __forceinline__ void gload16(const void* g, void* l) {
  __builtin_amdgcn_global_load_lds((void_g*)g, (void_l*)l, 16, 0, 0);
}

// ---------------- projection GEMM: C[m,n] = sum_k A[m,k]*W[n,k] + bias[n] --
// A: MMxDD f32, W: DDxDD f32 (both converted to f16 during reg-staging)
__global__ __launch_bounds__(256)
void proj_gemm(const float* __restrict__ Af, const float* __restrict__ Wf,
               const float* __restrict__ bias, f16* __restrict__ C) {
  __shared__ f16 As[128 * 32];
  __shared__ f16 Ws[128 * 32];
  const int m0 = blockIdx.x * 128;
  const int n0 = blockIdx.y * 128;
  const int t = threadIdx.x;
  const int lane = t & 63;
  const int w = t >> 6;
  const int wm = (w >> 1) * 64;
  const int wn = (w & 1) * 64;
  const int fr = lane & 15, fq = lane >> 4;
  const int xst = ((t >> 3) & 3) << 3;   // store-side swizzle (row = t>>2)
  const int xrd = ((fr >> 1) & 3) << 3;  // read-side swizzle (row = ..+fr)

  f32x4 acc[4][4] = {};

  const int e0 = t * 8;
  const int r0 = t >> 2, cW = (t & 3) * 8;
  const int e1 = 2048 + t * 8;

  for (int ks = 0; ks < 24; ++ks) {
    const int k0 = ks * 32;
    {
      const float* g0 = Wf + (size_t)(n0 + r0) * DD + k0 + cW;
      const float* g1 = Wf + (size_t)(n0 + 64 + r0) * DD + k0 + cW;
      float4 x0 = *(const float4*)g0, x1 = *(const float4*)(g0 + 4);
      float4 y0 = *(const float4*)g1, y1 = *(const float4*)(g1 + 4);
      f16x8 va, vb;
      va[0] = (f16)x0.x; va[1] = (f16)x0.y; va[2] = (f16)x0.z; va[3] = (f16)x0.w;
      va[4] = (f16)x1.x; va[5] = (f16)x1.y; va[6] = (f16)x1.z; va[7] = (f16)x1.w;
      vb[0] = (f16)y0.x; vb[1] = (f16)y0.y; vb[2] = (f16)y0.z; vb[3] = (f16)y0.w;
      vb[4] = (f16)y1.x; vb[5] = (f16)y1.y; vb[6] = (f16)y1.z; vb[7] = (f16)y1.w;
      *(f16x8*)&Ws[e0 ^ xst] = va;
      *(f16x8*)&Ws[e1 ^ xst] = vb;
    }
    {
      const float* g0 = Af + (size_t)(m0 + r0) * DD + k0 + cW;
      const float* g1 = Af + (size_t)(m0 + 64 + r0) * DD + k0 + cW;
      float4 x0 = *(const float4*)g0, x1 = *(const float4*)(g0 + 4);
      float4 y0 = *(const float4*)g1, y1 = *(const float4*)(g1 + 4);
      f16x8 va, vb;
      va[0] = (f16)x0.x; va[1] = (f16)x0.y; va[2] = (f16)x0.z; va[3] = (f16)x0.w;
      va[4] = (f16)x1.x; va[5] = (f16)x1.y; va[6] = (f16)x1.z; va[7] = (f16)x1.w;
      vb[0] = (f16)y0.x; vb[1] = (f16)y0.y; vb[2] = (f16)y0.z; vb[3] = (f16)y0.w;
      vb[4] = (f16)y1.x; vb[5] = (f16)y1.y; vb[6] = (f16)y1.z; vb[7] = (f16)y1.w;
      *(f16x8*)&As[e0 ^ xst] = va;
      *(f16x8*)&As[e1 ^ xst] = vb;
    }
    __syncthreads();

    f16x8 a[4], b[4];
#pragma unroll
    for (int i = 0; i < 4; ++i)
      a[i] = *(const f16x8*)&As[(((wm + i * 16 + fr) * 32) + fq * 8) ^ xrd];
#pragma unroll
    for (int j = 0; j < 4; ++j)
      b[j] = *(const f16x8*)&Ws[(((wn + j * 16 + fr) * 32) + fq * 8) ^ xrd];
#pragma unroll
    for (int i = 0; i < 4; ++i)
#pragma unroll
      for (int j = 0; j < 4; ++j)
        acc[i][j] = __builtin_amdgcn_mfma_f32_16x16x32_f16(a[i], b[j], acc[i][j], 0, 0, 0);
    __syncthreads();
  }

#pragma unroll
  for (int j = 0; j < 4; ++j) {
    const int col = n0 + wn + j * 16 + fr;
    const float bv = bias[col];
#pragma unroll
    for (int i = 0; i < 4; ++i) {
#pragma unroll
      for (int r = 0; r < 4; ++r) {
        const int row = m0 + wm + i * 16 + fq * 4 + r;
        C[(size_t)row * DD + col] = (f16)(acc[i][j][r] + bv);
      }
    }
  }
}

// ---------------- attn3: deep-pipelined QK^T row-stats -------------------
// Grid 256 (1 block/CU): bid = qs*16 + bb*2 + kh  (16 blocks sharing a K-half
// land on one XCD). Block 512 thr = 8 waves (2q x 4k). Block tile 256q x 256k,
// sweeping kt=0..7 over its 2048-k half; 96 flat d-step-64 iterations.
// Per iter: stage 64KB (Q+K) for t+1, vmcnt(8), barrier, 24 ds_read_b128 +
// 64 MFMA. Epilogue once per kt updates running (m,Z) per row + diagonal.
__global__ __launch_bounds__(512, 2)
void attn3(const f16* __restrict__ Q, const f16* __restrict__ K,
           const int* __restrict__ mask, float* __restrict__ pmv,
           float* __restrict__ pzv, float* __restrict__ sdg) {
  __shared__ f16 Qs[2][256 * 64];
  __shared__ f16 Ks[2][256 * 64];
  __shared__ float pms[4][256];
  __shared__ float pzs[4][256];

  const int bid = blockIdx.x;
  const int qs = bid >> 4, bb = (bid >> 1) & 7, kh = bid & 1;
  const int t = threadIdx.x, lane = t & 63, w = t >> 6;
  const int wq = w >> 2, wk = w & 3;
  const int fr = lane & 15, fq = lane >> 4;
  const int q0 = qs * 256;
  const float scale = 0.036084391824351613f;  // 1/sqrt(768)

  const f16* Qg = Q + ((size_t)bb * TT + q0) * DD;
  const f16* Kg = K + ((size_t)bb * TT + kh * 2048) * DD;

  // staging: per wave-issue 8 rows x 64 f16 (128B); lane -> row w*8+(lane>>3),
  // 16B slot lane&7; source column slot pre-swizzled by ^(row&7) = ^(lane>>3).
  const int rowq = w * 8 + (lane >> 3);
  const int csw  = ((lane & 7) ^ (lane >> 3)) * 8;
  const f16* qsb = Qg + (size_t)rowq * DD + csw;
  const f16* ksb = Kg + (size_t)rowq * DD + csw;

  // fragment read bases; read-side XOR matches (row&7) = (fr&7)
  const int arow = (wq * 128 + fr) * 64;
  const int brow = (wk * 64 + fr) * 64;
  const int swz0 = ((fq       ^ (fr & 7)) * 8);
  const int swz1 = (((4 + fq) ^ (fr & 7)) * 8);

  f32x4 acc[8][4] = {};
  float rmv = -1e30f, rzv = 0.f;

#define STAGE(bf, kt_, d0_) do { \
    _Pragma("unroll") \
    for (int r = 0; r < 4; ++r) { \
      gload16(qsb + (size_t)(r * 64) * DD + (d0_), &Qs[bf][(w * 8 + r * 64) * 64]); \
      gload16(ksb + (size_t)((kt_) * 256 + r * 64) * DD + (d0_), &Ks[bf][(w * 8 + r * 64) * 64]); \
    } \
  } while (0)

  STAGE(0, 0, 0);

  int kt = 0, st = 0;
  for (int it = 0; it < 96; ++it) {
    const int buf = it & 1;
    int nst = st + 1, nkt = kt;
    if (nst == 12) { nst = 0; ++nkt; }
    if (it < 95) {
      STAGE(buf ^ 1, nkt, nst * 64);
      asm volatile("s_waitcnt vmcnt(8)" ::: "memory");
    } else {
      asm volatile("s_waitcnt vmcnt(0)" ::: "memory");
    }
    __builtin_amdgcn_sched_barrier(0);
    __builtin_amdgcn_s_barrier();
    __builtin_amdgcn_sched_barrier(0);

#pragma unroll
    for (int ks = 0; ks < 2; ++ks) {
      const int sw = ks ? swz1 : swz0;
      f16x8 av[8], bv[4];
#pragma unroll
      for (int j = 0; j < 4; ++j)
        bv[j] = *(const f16x8*)&Ks[buf][brow + j * 1024 + sw];
#pragma unroll
      for (int i = 0; i < 8; ++i)
        av[i] = *(const f16x8*)&Qs[buf][arow + i * 1024 + sw];
#pragma unroll
      for (int i = 0; i < 8; ++i)
#pragma unroll
        for (int j = 0; j < 4; ++j)
          acc[i][j] = __builtin_amdgcn_mfma_f32_16x16x32_f16(av[i], bv[j], acc[i][j], 0, 0, 0);
    }

    if (st == 11) {
      // ---- per-kt epilogue: softmax partial over this 256-col strip ----
      const int kb = kh * 2048 + kt * 256;
      const float mb0 = mask[bb * TT + kb + wk * 64 + fr]      ? 0.f : -1e30f;
      const float mb1 = mask[bb * TT + kb + wk * 64 + 16 + fr] ? 0.f : -1e30f;
      const float mb2 = mask[bb * TT + kb + wk * 64 + 32 + fr] ? 0.f : -1e30f;
      const float mb3 = mask[bb * TT + kb + wk * 64 + 48 + fr] ? 0.f : -1e30f;
      const bool isdiag = (kh == (qs >> 3)) && (kt == (qs & 7));
#pragma unroll
      for (int i = 0; i < 8; ++i) {
#pragma unroll
        for (int rg = 0; rg < 4; ++rg) {
          float v0 = fmaf(acc[i][0][rg], scale, mb0);
          float v1 = fmaf(acc[i][1][rg], scale, mb1);
          float v2 = fmaf(acc[i][2][rg], scale, mb2);
          float v3 = fmaf(acc[i][3][rg], scale, mb3);
          if (isdiag) {
            const int rl = wq * 128 + i * 16 + fq * 4 + rg;
            const int cl = wk * 64 + fr;
            if (cl      == rl) sdg[(size_t)bb * TT + q0 + rl] = v0;
            if (cl + 16 == rl) sdg[(size_t)bb * TT + q0 + rl] = v1;
            if (cl + 32 == rl) sdg[(size_t)bb * TT + q0 + rl] = v2;
            if (cl + 48 == rl) sdg[(size_t)bb * TT + q0 + rl] = v3;
          }
          float mx = fmaxf(fmaxf(v0, v1), fmaxf(v2, v3));
#pragma unroll
          for (int off = 1; off < 16; off <<= 1)
            mx = fmaxf(mx, __shfl_xor(mx, off));
          float sz = __expf(v0 - mx) + __expf(v1 - mx) +
                     __expf(v2 - mx) + __expf(v3 - mx);
#pragma unroll
          for (int off = 1; off < 16; off <<= 1)
            sz += __shfl_xor(sz, off);
          if (fr == ((i * 4 + rg) & 15)) {
            const int row = wq * 128 + i * 16 + fq * 4 + rg;
            pms[wk][row] = mx;
            pzs[wk][row] = sz;
          }
        }
      }
#pragma unroll
      for (int i = 0; i < 8; ++i)
#pragma unroll
        for (int j = 0; j < 4; ++j)
          acc[i][j] = (f32x4)(0.f);
      asm volatile("s_waitcnt lgkmcnt(0)" ::: "memory");
      __builtin_amdgcn_sched_barrier(0);
      __builtin_amdgcn_s_barrier();
      __builtin_amdgcn_sched_barrier(0);
      if (t < 256) {
        float m0 = pms[0][t], m1 = pms[1][t], m2 = pms[2][t], m3 = pms[3][t];
        float m4 = fmaxf(fmaxf(m0, m1), fmaxf(m2, m3));
        float z4 = pzs[0][t] * __expf(m0 - m4) + pzs[1][t] * __expf(m1 - m4) +
                   pzs[2][t] * __expf(m2 - m4) + pzs[3][t] * __expf(m3 - m4);
        float mn = fmaxf(rmv, m4);
        rzv = rzv * __expf(rmv - mn) + z4 * __expf(m4 - mn);
        rmv = mn;
      }
      // pms/pzs reused only next kt (12 barriers away) — safe
    }

    __builtin_amdgcn_sched_barrier(0);
    __builtin_amdgcn_s_barrier();
    __builtin_amdgcn_sched_barrier(0);
    kt = nkt; st = nst;
  }
#undef STAGE

  if (t < 256) {
    pmv[(size_t)kh * MM + bb * TT + q0 + t] = rmv;
    pzv[(size_t)kh * MM + bb * TT + q0 + t] = rzv;
  }
}

// ---------------- merge 2 partials -> wdiag ----------------
__global__ void merge2(const float* __restrict__ pm, const float* __restrict__ pz,
                       const float* __restrict__ sdg, float* __restrict__ wdiag) {
  int i = blockIdx.x * 256 + threadIdx.x;
  if (i >= MM) return;
  float m0 = pm[i], m1 = pm[MM + i];
  float m = fmaxf(m0, m1);
  float Z = pz[i] * __expf(m0 - m) + pz[MM + i] * __expf(m1 - m);
  wdiag[i] = __expf(sdg[i] - m) / Z;
}

// ---------------- output ----------------
__global__ void zero_out(float* out, int n) {
  int i = blockIdx.x * 256 + threadIdx.x;
  if (i < n) out[i] = 0.f;
}

// out[b,d] = sum_t X[b,t,d] * wdiag[b,t]
__global__ __launch_bounds__(256)
void out_gemv(const float* __restrict__ X, const float* __restrict__ wdiag,
              float* __restrict__ out) {
  __shared__ float wsm[256];
  const int b = blockIdx.z;
  const int d = blockIdx.y * 256 + threadIdx.x;
  const int tbase = blockIdx.x * 256;
  wsm[threadIdx.x] = wdiag[b * TT + tbase + threadIdx.x];
  __syncthreads();
  float acc = 0.f;
  const float* xp = X + (size_t)(b * TT + tbase) * DD + d;
#pragma unroll 4
  for (int i = 0; i < 256; ++i) acc += xp[(size_t)i * DD] * wsm[i];
  atomicAdd(&out[b * DD + d], acc);
}

extern "C" void kernel_launch(void* const* d_in, const int* in_sizes, int n_in,
                              void* d_out, int out_size, void* d_ws, size_t ws_size,
                              hipStream_t stream) {
  const float* X    = (const float*)d_in[0];
  const int*   mask = (const int*)d_in[1];
  const float* Wq_w = (const float*)d_in[2];
  const float* Wq_b = (const float*)d_in[3];
  const float* Wk_w = (const float*)d_in[4];
  const float* Wk_b = (const float*)d_in[5];
  float* out = (float*)d_out;

  // workspace layout (~97 MB)
  f16* Qh  = (f16*)d_ws;
  f16* Kh  = Qh + (size_t)MM * DD;
  float* pm    = (float*)(Kh + (size_t)MM * DD);
  float* pz    = pm + 2 * (size_t)MM;
  float* sdg   = pz + 2 * (size_t)MM;
  float* wdiag = sdg + MM;

  proj_gemm<<<dim3(256, 6), 256, 0, stream>>>(X, Wq_w, Wq_b, Qh);
  proj_gemm<<<dim3(256, 6), 256, 0, stream>>>(X, Wk_w, Wk_b, Kh);

  attn3<<<256, 512, 0, stream>>>(Qh, Kh, mask, pm, pz, sdg);

  merge2<<<128, 256, 0, stream>>>(pm, pz, sdg, wdiag);

  zero_out<<<24, 256, 0, stream>>>(out, BB * DD);
  out_gemv<<<dim3(16, 3, 8), 256, 0, stream>>>(X, wdiag, out);
}